// Round 3
// baseline (586.695 us; speedup 1.0000x reference)
//
#include <hip/hip_runtime.h>
#include <stdint.h>

// ---------------------------------------------------------------------------
// MHA forward, MI355X/gfx950.
// Reference: proj(q,k,v) -> scores=QK^T/8 -> softmax (FULL row) -> mask-fill
// (post-softmax, -1e-9 where mask==0) -> PV -> out @ wout^T.   All fp32.
//
// Implementation: split-bf16 (hi/lo) MFMA everywhere: a*b ~= ahi*bhi +
// ahi*blo + alo*bhi  (rel err ~2^-17/term, fp32-class end-to-end ~1e-4 abs).
// The -1e-9 masked-fill value is approximated by 0: its contribution to the
// final output is ~3e-8 absolute (below fp32 reorder noise).
//
// MFMA fragments use the guide-verified short8 form (bf16 bits in shorts).
// Workspace guarded: if ws_size < 112 MB nothing launches (clean fail, not
// a container-killing OOB scribble).
// ---------------------------------------------------------------------------

#define BATCH  2
#define S_LEN  2048
#define DMODEL 1024
#define NH     16
#define HD     64

typedef __bf16 bf16_t;
typedef short  short8 __attribute__((ext_vector_type(8)));   // 8 x bf16 bits
typedef float  f32x4  __attribute__((ext_vector_type(4)));

#define AS1 __attribute__((address_space(1)))
#define AS3 __attribute__((address_space(3)))

static constexpr size_t MB = (size_t)1 << 20;
static constexpr size_t WS_REQUIRED = 112 * MB;
// Workspace layout (byte offsets). High-water: 112 MB.
//  0..48MB   : input splits qx/kx/vx (hi,lo)   [dead after projections]
//  0..16MB   : (reused) attention output O (hi,lo)
//  48..64MB  : weight splits wq,wk,wv,wout (hi,lo)
//  64..112MB : Q (pre-scaled 1/8), K as [B,H,S,hd]; V transposed [B,H,hd,S]
#define OFF_XHI(z)  ((size_t)(z) * 16 * MB)
#define OFF_XLO(z)  (OFF_XHI(z) + 8 * MB)
#define OFF_WHI(z)  (48 * MB + (size_t)(z) * 4 * MB)
#define OFF_WLO(z)  (OFF_WHI(z) + 2 * MB)
#define OFF_PHI(z)  (64 * MB + (size_t)(z) * 16 * MB)   // z=0:Q 1:K 2:VT
#define OFF_PLO(z)  (OFF_PHI(z) + 8 * MB)
#define OFF_OHI     ((size_t)0)
#define OFF_OLO     (8 * MB)

__device__ __forceinline__ f32x4 mfma_bf16(short8 a, short8 b, f32x4 c) {
    return __builtin_amdgcn_mfma_f32_16x16x32_bf16(a, b, c, 0, 0, 0);
}

__device__ __forceinline__ short8 ld8(const bf16_t* p) {
    return *reinterpret_cast<const short8*>(p);
}

// ---------------------------------------------------------------------------
// fp32 -> (bf16 hi, bf16 lo) split conversion, vectorized float4.
// ---------------------------------------------------------------------------
__global__ void cvt_split_kernel(const float* __restrict__ x,
                                 bf16_t* __restrict__ hi, bf16_t* __restrict__ lo,
                                 int n) {
    int i = (blockIdx.x * blockDim.x + threadIdx.x) * 4;
    if (i >= n) return;
    const float4 v = *reinterpret_cast<const float4*>(x + i);
    float s[4] = {v.x, v.y, v.z, v.w};
    ushort hbits[4], lbits[4];
#pragma unroll
    for (int j = 0; j < 4; j++) {
        bf16_t hh = (bf16_t)s[j];
        bf16_t ll = (bf16_t)(s[j] - (float)hh);
        hbits[j] = __builtin_bit_cast(ushort, hh);
        lbits[j] = __builtin_bit_cast(ushort, ll);
    }
    *reinterpret_cast<ushort4*>(hi + i) = ushort4{hbits[0], hbits[1], hbits[2], hbits[3]};
    *reinterpret_cast<ushort4*>(lo + i) = ushort4{lbits[0], lbits[1], lbits[2], lbits[3]};
}

// ---------------------------------------------------------------------------
// Split-bf16 GEMM, C = A @ B^T (both operands K-contiguous), K=1024 done as
// 3 segments {(Ahi,Bhi),(Ahi,Blo),(Alo,Bhi)}.  128x128 tile, BK=32,
// 256 threads = 4 waves (2x2), each wave 64x64 = 4x4 16x16x32 frags.
// FINAL=0: grid.z picks q/k/v; epilogue writes head-split hi/lo (Q scaled
//          1/8; V transposed).  FINAL=1: output projection, fp32 -> d_out.
// ---------------------------------------------------------------------------
template <int FINAL>
__global__ __launch_bounds__(256, 2) void gemm_split_kernel(char* __restrict__ ws,
                                                            float* __restrict__ fout) {
    __shared__ __align__(16) bf16_t As[128 * 32];
    __shared__ __align__(16) bf16_t Bs[128 * 32];

    const int z = FINAL ? 3 : blockIdx.z;
    const bf16_t* Ahi = FINAL ? (const bf16_t*)(ws + OFF_OHI) : (const bf16_t*)(ws + OFF_XHI(z));
    const bf16_t* Alo = FINAL ? (const bf16_t*)(ws + OFF_OLO) : (const bf16_t*)(ws + OFF_XLO(z));
    const bf16_t* Bhi = (const bf16_t*)(ws + OFF_WHI(z));
    const bf16_t* Blo = (const bf16_t*)(ws + OFF_WLO(z));
    bf16_t* Ohi = FINAL ? nullptr : (bf16_t*)(ws + OFF_PHI(z));
    bf16_t* Olo = FINAL ? nullptr : (bf16_t*)(ws + OFF_PLO(z));
    const float scale = (!FINAL && z == 0) ? 0.125f : 1.0f;  // 1/sqrt(hd) folded into Q

    const int tid = threadIdx.x;
    const int lane = tid & 63, w = tid >> 6;
    const int wr = w >> 1, wc = w & 1;
    const int fr = lane & 15, fg = lane >> 4;
    const int m0 = blockIdx.x * 128, n0 = blockIdx.y * 128;
    const int K = 1024;

    const bf16_t* Aseg[3] = {Ahi, Ahi, Alo};
    const bf16_t* Bseg[3] = {Bhi, Blo, Bhi};

    f32x4 acc[4][4];
#pragma unroll
    for (int i = 0; i < 4; i++)
#pragma unroll
        for (int j = 0; j < 4; j++) acc[i][j] = f32x4{0.f, 0.f, 0.f, 0.f};

    AS3 bf16_t* asA = (AS3 bf16_t*)As;
    AS3 bf16_t* asB = (AS3 bf16_t*)Bs;

#pragma unroll 1
    for (int seg = 0; seg < 3; ++seg) {
        const bf16_t* Ab = Aseg[seg];
        const bf16_t* Bb = Bseg[seg];
#pragma unroll 1
        for (int ks = 0; ks < K; ks += 32) {
            __syncthreads();  // previous compute done before restaging
#pragma unroll
            for (int i = 0; i < 2; i++) {
                // chunk c covers 16B: LDS byte c*16; global row c/4, 16B col (c&3)*16
                const int c = i * 256 + tid;
                const int row = c >> 2;
                const int ce = (c & 3) * 8;  // element offset within row
                __builtin_amdgcn_global_load_lds((const AS1 void*)(Ab + (size_t)(m0 + row) * K + ks + ce),
                                                 (AS3 void*)(asA + (size_t)(i * 256 + w * 64) * 8),
                                                 16, 0, 0);
                __builtin_amdgcn_global_load_lds((const AS1 void*)(Bb + (size_t)(n0 + row) * K + ks + ce),
                                                 (AS3 void*)(asB + (size_t)(i * 256 + w * 64) * 8),
                                                 16, 0, 0);
            }
            __syncthreads();  // staging visible (syncthreads drains vmcnt)

            short8 af[4], bfr[4];
#pragma unroll
            for (int i = 0; i < 4; i++) {
                af[i]  = ld8(&As[(wr * 64 + i * 16 + fr) * 32 + fg * 8]);
                bfr[i] = ld8(&Bs[(wc * 64 + i * 16 + fr) * 32 + fg * 8]);
            }
#pragma unroll
            for (int i = 0; i < 4; i++)
#pragma unroll
                for (int j = 0; j < 4; j++)
                    acc[i][j] = mfma_bf16(af[i], bfr[j], acc[i][j]);
        }
    }

    // Epilogue. C/D frag: col = lane&15, row = (lane>>4)*4 + reg  [HW-verified]
#pragma unroll
    for (int i = 0; i < 4; i++) {
#pragma unroll
        for (int j = 0; j < 4; j++) {
            const int ncol = n0 + wc * 64 + j * 16 + fr;
#pragma unroll
            for (int r = 0; r < 4; r++) {
                const int m = m0 + wr * 64 + i * 16 + fg * 4 + r;
                const float val = acc[i][j][r] * scale;
                if (FINAL) {
                    fout[(size_t)m * DMODEL + ncol] = val;
                } else {
                    const bf16_t h = (bf16_t)val;
                    const bf16_t l = (bf16_t)(val - (float)h);
                    const int b = m >> 11, s = m & (S_LEN - 1);
                    const int hh = ncol >> 6, d = ncol & (HD - 1);
                    size_t idx;
                    if (z == 2) idx = ((size_t)(b * NH + hh) * HD + d) * S_LEN + s;      // VT [B,H,hd,S]
                    else        idx = ((size_t)(b * NH + hh) * S_LEN + s) * HD + d;      // [B,H,S,hd]
                    Ohi[idx] = h;
                    Olo[idx] = l;
                }
            }
        }
    }
}

// ---------------------------------------------------------------------------
// Flash attention with post-softmax mask.  Grid: (S/128, B*H), 256 threads.
// 4 independent waves/block, each owns 32 q-rows; no cross-wave coupling.
// K/V read directly from global (L2-resident per (b,h): 1MB << 4MB L2).
// P transposed D-layout -> A-layout via per-wave LDS stripe (row stride 72).
// ---------------------------------------------------------------------------
__global__ __launch_bounds__(256, 2) void attn_kernel(char* __restrict__ ws,
                                                      const int* __restrict__ mask) {
    __shared__ __align__(16) bf16_t Ph[128 * 72];
    __shared__ __align__(16) bf16_t Pl[128 * 72];

    const bf16_t* Qhi = (const bf16_t*)(ws + OFF_PHI(0));
    const bf16_t* Qlo = (const bf16_t*)(ws + OFF_PLO(0));
    const bf16_t* Khi = (const bf16_t*)(ws + OFF_PHI(1));
    const bf16_t* Klo = (const bf16_t*)(ws + OFF_PLO(1));
    const bf16_t* Vhi = (const bf16_t*)(ws + OFF_PHI(2));
    const bf16_t* Vlo = (const bf16_t*)(ws + OFF_PLO(2));
    bf16_t* Ohi = (bf16_t*)(ws + OFF_OHI);
    bf16_t* Olo = (bf16_t*)(ws + OFF_OLO);

    const int tid = threadIdx.x, lane = tid & 63, w = tid >> 6;
    const int fr = lane & 15, fg = lane >> 4;
    const int bh = blockIdx.y;
    const int q0 = blockIdx.x * 128;
    const size_t qkBase = (size_t)bh * S_LEN * HD;
    const size_t vtBase = (size_t)bh * HD * S_LEN;

    // Q fragments (Q pre-scaled by 1/8 at projection epilogue)
    short8 qh[2][2], ql[2][2];
#pragma unroll
    for (int mf = 0; mf < 2; mf++) {
        const int qr = q0 + w * 32 + mf * 16 + fr;
#pragma unroll
        for (int kc = 0; kc < 2; kc++) {
            const size_t off = qkBase + (size_t)qr * HD + kc * 32 + fg * 8;
            qh[mf][kc] = ld8(Qhi + off);
            ql[mf][kc] = ld8(Qlo + off);
        }
    }

    f32x4 acco[2][4];
#pragma unroll
    for (int mf = 0; mf < 2; mf++)
#pragma unroll
        for (int df = 0; df < 4; df++) acco[mf][df] = f32x4{0.f, 0.f, 0.f, 0.f};
    float mrun[2][4], lrun[2][4];
#pragma unroll
    for (int mf = 0; mf < 2; mf++)
#pragma unroll
        for (int r = 0; r < 4; r++) { mrun[mf][r] = -__builtin_inff(); lrun[mf][r] = 0.f; }

#pragma unroll 1
    for (int k0 = 0; k0 < S_LEN; k0 += 64) {
        // ---- scores: S = Q K^T (already scaled), split 3-MFMA, hd = 2 x K32
        f32x4 sacc[2][4];
#pragma unroll
        for (int mf = 0; mf < 2; mf++)
#pragma unroll
            for (int cf = 0; cf < 4; cf++) sacc[mf][cf] = f32x4{0.f, 0.f, 0.f, 0.f};
#pragma unroll
        for (int cf = 0; cf < 4; cf++) {
            const int kk = k0 + cf * 16 + fr;
#pragma unroll
            for (int kc = 0; kc < 2; kc++) {
                const size_t off = qkBase + (size_t)kk * HD + kc * 32 + fg * 8;
                const short8 kh = ld8(Khi + off);
                const short8 kl = ld8(Klo + off);
#pragma unroll
                for (int mf = 0; mf < 2; mf++) {
                    sacc[mf][cf] = mfma_bf16(qh[mf][kc], kh, sacc[mf][cf]);
                    sacc[mf][cf] = mfma_bf16(qh[mf][kc], kl, sacc[mf][cf]);
                    sacc[mf][cf] = mfma_bf16(ql[mf][kc], kh, sacc[mf][cf]);
                }
            }
        }

        // previous tile's PV ds_reads complete before overwriting P stripe
        asm volatile("s_waitcnt lgkmcnt(0)" ::: "memory");

        // ---- online softmax over FULL row (mask is post-softmax), then
        //      write masked P (hi/lo) into this wave's LDS stripe.
#pragma unroll
        for (int mf = 0; mf < 2; mf++) {
#pragma unroll
            for (int r = 0; r < 4; r++) {
                float mx = fmaxf(fmaxf(sacc[mf][0][r], sacc[mf][1][r]),
                                 fmaxf(sacc[mf][2][r], sacc[mf][3][r]));
                mx = fmaxf(mx, __shfl_xor(mx, 1, 64));
                mx = fmaxf(mx, __shfl_xor(mx, 2, 64));
                mx = fmaxf(mx, __shfl_xor(mx, 4, 64));
                mx = fmaxf(mx, __shfl_xor(mx, 8, 64));
                const float mnew = fmaxf(mrun[mf][r], mx);
                const float alpha = __expf(mrun[mf][r] - mnew);
                mrun[mf][r] = mnew;
                float psum = 0.f;
#pragma unroll
                for (int cf = 0; cf < 4; cf++) {
                    const float p = __expf(sacc[mf][cf][r] - mnew);
                    sacc[mf][cf][r] = p;
                    psum += p;
                }
                psum += __shfl_xor(psum, 1, 64);
                psum += __shfl_xor(psum, 2, 64);
                psum += __shfl_xor(psum, 4, 64);
                psum += __shfl_xor(psum, 8, 64);
                lrun[mf][r] = lrun[mf][r] * alpha + psum;
#pragma unroll
                for (int df = 0; df < 4; df++) acco[mf][df][r] *= alpha;

                const int qrl = w * 32 + mf * 16 + fg * 4 + r;
                const int64_t mrow = (int64_t)(q0 + qrl) * S_LEN + k0;
#pragma unroll
                for (int cf = 0; cf < 4; cf++) {
                    const int kcol = cf * 16 + fr;
                    const float pm = mask[mrow + kcol] ? sacc[mf][cf][r] : 0.f;
                    const bf16_t h = (bf16_t)pm;
                    Ph[qrl * 72 + kcol] = h;
                    Pl[qrl * 72 + kcol] = (bf16_t)(pm - (float)h);
                }
            }
        }

        // P writes land before A-layout re-read (same wave, in-order DS)
        asm volatile("s_waitcnt lgkmcnt(0)" ::: "memory");

        // ---- PV accumulate: A = masked P (LDS), B = V^T (global, K-contig)
#pragma unroll
        for (int kc2 = 0; kc2 < 2; kc2++) {
            short8 pah[2], pal[2];
#pragma unroll
            for (int mf = 0; mf < 2; mf++) {
                const int prow = w * 32 + mf * 16 + fr;
                pah[mf] = ld8(&Ph[prow * 72 + kc2 * 32 + fg * 8]);
                pal[mf] = ld8(&Pl[prow * 72 + kc2 * 32 + fg * 8]);
            }
#pragma unroll
            for (int df = 0; df < 4; df++) {
                const size_t voff = vtBase + (size_t)(df * 16 + fr) * S_LEN + k0 + kc2 * 32 + fg * 8;
                const short8 vh = ld8(Vhi + voff);
                const short8 vl = ld8(Vlo + voff);
#pragma unroll
                for (int mf = 0; mf < 2; mf++) {
                    acco[mf][df] = mfma_bf16(pah[mf], vh, acco[mf][df]);
                    acco[mf][df] = mfma_bf16(pah[mf], vl, acco[mf][df]);
                    acco[mf][df] = mfma_bf16(pal[mf], vh, acco[mf][df]);
                }
            }
        }
    }

    // ---- epilogue: normalize, split to hi/lo, store O as [B,S,D]
    const int b = bh >> 4, hh = bh & (NH - 1);
#pragma unroll
    for (int mf = 0; mf < 2; mf++) {
#pragma unroll
        for (int r = 0; r < 4; r++) {
            const int qrow = q0 + w * 32 + mf * 16 + fg * 4 + r;
            const float inv = 1.0f / lrun[mf][r];
#pragma unroll
            for (int df = 0; df < 4; df++) {
                const float o = acco[mf][df][r] * inv;
                const bf16_t h = (bf16_t)o;
                const size_t idx = ((size_t)b * S_LEN + qrow) * DMODEL + hh * HD + df * 16 + fr;
                Ohi[idx] = h;
                Olo[idx] = (bf16_t)(o - (float)h);
            }
        }
    }
}

// ---------------------------------------------------------------------------
extern "C" void kernel_launch(void* const* d_in, const int* in_sizes, int n_in,
                              void* d_out, int out_size, void* d_ws, size_t ws_size,
                              hipStream_t stream) {
    (void)in_sizes; (void)n_in; (void)out_size;
    if (ws_size < WS_REQUIRED) return;  // clean incorrect-output signal, not an OOB crash

    const float* q    = (const float*)d_in[0];
    const float* k    = (const float*)d_in[1];
    const float* v    = (const float*)d_in[2];
    const int*   mask = (const int*)  d_in[3];
    const float* wq   = (const float*)d_in[4];
    const float* wk   = (const float*)d_in[5];
    const float* wv   = (const float*)d_in[6];
    const float* wout = (const float*)d_in[7];
    char* ws = (char*)d_ws;
    float* out = (float*)d_out;

    const size_t nX = (size_t)BATCH * S_LEN * DMODEL;  // 4,194,304
    const size_t nW = (size_t)DMODEL * DMODEL;         // 1,048,576
    const dim3 blk(256);

    // fp32 -> hi/lo splits
    cvt_split_kernel<<<dim3(nX / 1024), blk, 0, stream>>>(q, (bf16_t*)(ws + OFF_XHI(0)), (bf16_t*)(ws + OFF_XLO(0)), (int)nX);
    cvt_split_kernel<<<dim3(nX / 1024), blk, 0, stream>>>(k, (bf16_t*)(ws + OFF_XHI(1)), (bf16_t*)(ws + OFF_XLO(1)), (int)nX);
    cvt_split_kernel<<<dim3(nX / 1024), blk, 0, stream>>>(v, (bf16_t*)(ws + OFF_XHI(2)), (bf16_t*)(ws + OFF_XLO(2)), (int)nX);
    cvt_split_kernel<<<dim3(nW / 1024), blk, 0, stream>>>(wq,   (bf16_t*)(ws + OFF_WHI(0)), (bf16_t*)(ws + OFF_WLO(0)), (int)nW);
    cvt_split_kernel<<<dim3(nW / 1024), blk, 0, stream>>>(wk,   (bf16_t*)(ws + OFF_WHI(1)), (bf16_t*)(ws + OFF_WLO(1)), (int)nW);
    cvt_split_kernel<<<dim3(nW / 1024), blk, 0, stream>>>(wv,   (bf16_t*)(ws + OFF_WHI(2)), (bf16_t*)(ws + OFF_WLO(2)), (int)nW);
    cvt_split_kernel<<<dim3(nW / 1024), blk, 0, stream>>>(wout, (bf16_t*)(ws + OFF_WHI(3)), (bf16_t*)(ws + OFF_WLO(3)), (int)nW);

    // q/k/v projections (z = 0/1/2), head-split epilogues
    gemm_split_kernel<0><<<dim3(32, 8, 3), blk, 0, stream>>>(ws, nullptr);

    // flash attention with post-softmax mask
    attn_kernel<<<dim3(S_LEN / 128, BATCH * NH), blk, 0, stream>>>(ws, mask);

    // output projection -> d_out (fp32)
    gemm_split_kernel<1><<<dim3(32, 8, 1), blk, 0, stream>>>(ws, out);
}